// Round 9
// baseline (130.947 us; speedup 1.0000x reference)
//
#include <hip/hip_runtime.h>

#define D 64  // feature dim for all layers

#define NB 256   // level-1 edge-partition blocks
#define RB 256   // radix bins (dst>>8)
#define P2CAP 20 // register-cached records per thread in p2

// ---------------------------------------------------------------------------
// helpers
// ---------------------------------------------------------------------------
__device__ inline float4 f4zero() { return make_float4(0.f, 0.f, 0.f, 0.f); }

__device__ inline float4 xor_add(float4 a, int m) {
  a.x += __shfl_xor(a.x, m);
  a.y += __shfl_xor(a.y, m);
  a.z += __shfl_xor(a.z, m);
  a.w += __shfl_xor(a.w, m);
  return a;
}

// gather partial sums for one node: lane-group g (of 4) takes edges == g mod 4,
// 16 edges in flight per wave-iteration (4 per lane), c4 = channel quad.
__device__ inline float4 gather_rows(
    const float* __restrict__ H, const int2* __restrict__ pairs,
    int beg, int end, int g, int c4) {
  float4 a0 = f4zero(), a1 = f4zero(), a2 = f4zero(), a3 = f4zero();
  int i = beg + g;
  for (; i + 12 < end; i += 16) {
    const int2 p0 = pairs[i];
    const int2 p1 = pairs[i + 4];
    const int2 p2 = pairs[i + 8];
    const int2 p3 = pairs[i + 12];
    const float4 v0 = *reinterpret_cast<const float4*>(H + (size_t)p0.x * D + c4 * 4);
    const float4 v1 = *reinterpret_cast<const float4*>(H + (size_t)p1.x * D + c4 * 4);
    const float4 v2 = *reinterpret_cast<const float4*>(H + (size_t)p2.x * D + c4 * 4);
    const float4 v3 = *reinterpret_cast<const float4*>(H + (size_t)p3.x * D + c4 * 4);
    const float w0 = __int_as_float(p0.y), w1 = __int_as_float(p1.y);
    const float w2 = __int_as_float(p2.y), w3 = __int_as_float(p3.y);
    a0.x += w0 * v0.x; a0.y += w0 * v0.y; a0.z += w0 * v0.z; a0.w += w0 * v0.w;
    a1.x += w1 * v1.x; a1.y += w1 * v1.y; a1.z += w1 * v1.z; a1.w += w1 * v1.w;
    a2.x += w2 * v2.x; a2.y += w2 * v2.y; a2.z += w2 * v2.z; a2.w += w2 * v2.w;
    a3.x += w3 * v3.x; a3.y += w3 * v3.y; a3.z += w3 * v3.z; a3.w += w3 * v3.w;
  }
  for (; i < end; i += 4) {
    const int2 p = pairs[i];
    const float4 v = *reinterpret_cast<const float4*>(H + (size_t)p.x * D + c4 * 4);
    const float w = __int_as_float(p.y);
    a0.x += w * v.x; a0.y += w * v.y; a0.z += w * v.z; a0.w += w * v.w;
  }
  float4 a;
  a.x = (a0.x + a1.x) + (a2.x + a3.x);
  a.y = (a0.y + a1.y) + (a2.y + a3.y);
  a.z = (a0.z + a1.z) + (a2.z + a3.z);
  a.w = (a0.w + a1.w) + (a2.w + a3.w);
  return a;
}

// ---------------------------------------------------------------------------
// GEMM: out = f(A) @ W  (generic/fallback paths)
// ---------------------------------------------------------------------------
template <bool PRE>
__global__ __launch_bounds__(256, 4) void gemm64_kernel(
    const float* __restrict__ A, const float* __restrict__ W,
    const float* __restrict__ bpre, float* __restrict__ out, int N) {
  __shared__ float sA[64][68];
  __shared__ float sW[64][68];
  const int t = threadIdx.x;
  const int rowBase = blockIdx.x * 64;

#pragma unroll
  for (int i = t * 4; i < 4096; i += 1024) {
    const int k = i >> 6, c = i & 63;
    *reinterpret_cast<float4*>(&sW[k][c]) =
        *reinterpret_cast<const float4*>(W + i);
  }
#pragma unroll
  for (int i = t * 4; i < 4096; i += 1024) {
    const int r = i >> 6, k = i & 63;
    const int row = rowBase + r;
    float4 a = f4zero();
    if (row < N) a = *reinterpret_cast<const float4*>(A + (size_t)row * D + k);
    if (PRE) {
      const float4 b = *reinterpret_cast<const float4*>(bpre + k);
      a.x = fmaxf(a.x + b.x, 0.f);
      a.y = fmaxf(a.y + b.y, 0.f);
      a.z = fmaxf(a.z + b.z, 0.f);
      a.w = fmaxf(a.w + b.w, 0.f);
    }
    *reinterpret_cast<float4*>(&sA[r][k]) = a;
  }
  __syncthreads();

  const int ty = t >> 4, tx = t & 15;
  float4 acc0 = f4zero(), acc1 = f4zero(), acc2 = f4zero(), acc3 = f4zero();

#pragma unroll 4
  for (int kq = 0; kq < 16; ++kq) {
    const float4 w0 = *reinterpret_cast<const float4*>(&sW[kq * 4 + 0][tx * 4]);
    const float4 w1 = *reinterpret_cast<const float4*>(&sW[kq * 4 + 1][tx * 4]);
    const float4 w2 = *reinterpret_cast<const float4*>(&sW[kq * 4 + 2][tx * 4]);
    const float4 w3 = *reinterpret_cast<const float4*>(&sW[kq * 4 + 3][tx * 4]);
    const float4 a0 = *reinterpret_cast<const float4*>(&sA[ty * 4 + 0][kq * 4]);
    const float4 a1 = *reinterpret_cast<const float4*>(&sA[ty * 4 + 1][kq * 4]);
    const float4 a2 = *reinterpret_cast<const float4*>(&sA[ty * 4 + 2][kq * 4]);
    const float4 a3 = *reinterpret_cast<const float4*>(&sA[ty * 4 + 3][kq * 4]);
#define FMA4(ACC, AV)                                                     \
    ACC.x += AV.x * w0.x + AV.y * w1.x + AV.z * w2.x + AV.w * w3.x;       \
    ACC.y += AV.x * w0.y + AV.y * w1.y + AV.z * w2.y + AV.w * w3.y;       \
    ACC.z += AV.x * w0.z + AV.y * w1.z + AV.z * w2.z + AV.w * w3.z;       \
    ACC.w += AV.x * w0.w + AV.y * w1.w + AV.z * w2.w + AV.w * w3.w;
    FMA4(acc0, a0) FMA4(acc1, a1) FMA4(acc2, a2) FMA4(acc3, a3)
#undef FMA4
  }

  const int row0 = rowBase + ty * 4;
  if (row0 + 0 < N) *reinterpret_cast<float4*>(out + (size_t)(row0 + 0) * D + tx * 4) = acc0;
  if (row0 + 1 < N) *reinterpret_cast<float4*>(out + (size_t)(row0 + 1) * D + tx * 4) = acc1;
  if (row0 + 2 < N) *reinterpret_cast<float4*>(out + (size_t)(row0 + 2) * D + tx * 4) = acc2;
  if (row0 + 3 < N) *reinterpret_cast<float4*>(out + (size_t)(row0 + 3) * D + tx * 4) = acc3;
}

// ---------------------------------------------------------------------------
// MERGED kernel 1 (radix path): blocks [0,NB) coarse-histogram; rest gemm1.
// ---------------------------------------------------------------------------
__global__ __launch_bounds__(256, 4) void hist_gemm_kernel(
    const int* __restrict__ dst, int* __restrict__ countsB, int E, int epb,
    const float* __restrict__ A, const float* __restrict__ W,
    float* __restrict__ out, int N) {
  __shared__ float sA[64][68];
  __shared__ float sW[64][68];
  const int t = threadIdx.x;

  if ((int)blockIdx.x < NB) {
    int* h = reinterpret_cast<int*>(&sA[0][0]);
    h[t] = 0;
    __syncthreads();
    const int base = blockIdx.x * epb;
    const int lim = min(base + epb, E);
    for (int i = base + t; i < lim; i += 256) atomicAdd(&h[dst[i] >> 8], 1);
    __syncthreads();
    countsB[blockIdx.x * RB + t] = h[t];
    return;
  }

  const int rowBase = ((int)blockIdx.x - NB) * 64;
#pragma unroll
  for (int i = t * 4; i < 4096; i += 1024) {
    const int k = i >> 6, c = i & 63;
    *reinterpret_cast<float4*>(&sW[k][c]) =
        *reinterpret_cast<const float4*>(W + i);
  }
#pragma unroll
  for (int i = t * 4; i < 4096; i += 1024) {
    const int r = i >> 6, k = i & 63;
    const int row = rowBase + r;
    float4 a = f4zero();
    if (row < N) a = *reinterpret_cast<const float4*>(A + (size_t)row * D + k);
    *reinterpret_cast<float4*>(&sA[r][k]) = a;
  }
  __syncthreads();

  const int ty = t >> 4, tx = t & 15;
  float4 acc0 = f4zero(), acc1 = f4zero(), acc2 = f4zero(), acc3 = f4zero();

#pragma unroll 4
  for (int kq = 0; kq < 16; ++kq) {
    const float4 w0 = *reinterpret_cast<const float4*>(&sW[kq * 4 + 0][tx * 4]);
    const float4 w1 = *reinterpret_cast<const float4*>(&sW[kq * 4 + 1][tx * 4]);
    const float4 w2 = *reinterpret_cast<const float4*>(&sW[kq * 4 + 2][tx * 4]);
    const float4 w3 = *reinterpret_cast<const float4*>(&sW[kq * 4 + 3][tx * 4]);
    const float4 a0 = *reinterpret_cast<const float4*>(&sA[ty * 4 + 0][kq * 4]);
    const float4 a1 = *reinterpret_cast<const float4*>(&sA[ty * 4 + 1][kq * 4]);
    const float4 a2 = *reinterpret_cast<const float4*>(&sA[ty * 4 + 2][kq * 4]);
    const float4 a3 = *reinterpret_cast<const float4*>(&sA[ty * 4 + 3][kq * 4]);
#define FMA4(ACC, AV)                                                     \
    ACC.x += AV.x * w0.x + AV.y * w1.x + AV.z * w2.x + AV.w * w3.x;       \
    ACC.y += AV.x * w0.y + AV.y * w1.y + AV.z * w2.y + AV.w * w3.y;       \
    ACC.z += AV.x * w0.z + AV.y * w1.z + AV.z * w2.z + AV.w * w3.z;       \
    ACC.w += AV.x * w0.w + AV.y * w1.w + AV.z * w2.w + AV.w * w3.w;
    FMA4(acc0, a0) FMA4(acc1, a1) FMA4(acc2, a2) FMA4(acc3, a3)
#undef FMA4
  }

  const int row0 = rowBase + ty * 4;
  if (row0 + 0 < N) *reinterpret_cast<float4*>(out + (size_t)(row0 + 0) * D + tx * 4) = acc0;
  if (row0 + 1 < N) *reinterpret_cast<float4*>(out + (size_t)(row0 + 1) * D + tx * 4) = acc1;
  if (row0 + 2 < N) *reinterpret_cast<float4*>(out + (size_t)(row0 + 2) * D + tx * 4) = acc2;
  if (row0 + 3 < N) *reinterpret_cast<float4*>(out + (size_t)(row0 + 3) * D + tx * 4) = acc3;
}

// ---------------------------------------------------------------------------
// p1_scatter (radix): derives bin bases from block-major countsB, scatters
// records into coarse buckets. Block 0 publishes binBase[257] for p2.
// ---------------------------------------------------------------------------
__global__ __launch_bounds__(256) void p1_scatter_kernel(
    const int* __restrict__ src, const int* __restrict__ dst,
    const float* __restrict__ ew, const int* __restrict__ countsB,
    int* __restrict__ binBaseG, int2* __restrict__ tmp, int E, int epb) {
  __shared__ int s[RB];
  __shared__ int cur[RB];
  const int t = threadIdx.x;
  const int b = blockIdx.x;

  int total = 0, pre = 0;
#pragma unroll 8
  for (int i = 0; i < NB; ++i) {
    const int c = countsB[i * RB + t];
    if (i == b) pre = total;
    total += c;
  }
  s[t] = total;
  __syncthreads();
  for (int off = 1; off < 256; off <<= 1) {
    int x = (t >= off) ? s[t - off] : 0;
    __syncthreads();
    s[t] += x;
    __syncthreads();
  }
  const int binBase = s[t] - total;
  cur[t] = binBase + pre;
  if (b == 0) {
    binBaseG[t] = binBase;
    if (t == 255) binBaseG[256] = s[255];
  }
  __syncthreads();

  const int base = b * epb;
  const int lim = min(base + epb, E);
  for (int i = base + t; i < lim; i += 256) {
    const int d = dst[i];
    const unsigned sv = (unsigned)src[i];
    const float w = ew[i];
    const int pos = atomicAdd(&cur[d >> 8], 1);   // LDS atomic
    tmp[pos] = make_int2((int)((unsigned)d | (sv << 16)), __float_as_int(w));
  }
}

// ---------------------------------------------------------------------------
// p2 (radix): SINGLE global pass. Records + their LDS-atomic ranks cached in
// registers (statically indexed, P2CAP each); overflow ranks spill to rankG
// (never hit at this distribution). Write pos = base[key] + rank.
// ---------------------------------------------------------------------------
__global__ __launch_bounds__(256) void p2_kernel(
    const int2* __restrict__ tmp, const int* __restrict__ binBaseG,
    int* __restrict__ rankG,
    int* __restrict__ offs, int2* __restrict__ pairs, int N) {
  __shared__ int h[RB];
  __shared__ int s[RB];
  const int t = threadIdx.x;
  const int b = blockIdx.x;
  const int segBeg = binBaseG[b];
  const int segEnd = binBaseG[b + 1];
  const int segLen = segEnd - segBeg;

  h[t] = 0;
  __syncthreads();

  // pass 1: histogram + cache records & ranks in registers
  const int cnt = (segLen - t + 255) >> 8;   // my record count (>=0)
  int2 rec[P2CAP];
  int  rk[P2CAP];
#pragma unroll
  for (int k = 0; k < P2CAP; ++k) {
    if (k < cnt) {
      const int i = segBeg + t + (k << 8);
      const int2 r = tmp[i];
      rec[k] = r;
      rk[k] = atomicAdd(&h[r.x & 255], 1);
    }
  }
  for (int i = segBeg + (P2CAP << 8) + t; i < segEnd; i += 256)
    rankG[i] = atomicAdd(&h[tmp[i].x & 255], 1);   // overflow (rare)
  __syncthreads();

  // exclusive scan of h
  const int v = h[t];
  s[t] = v;
  __syncthreads();
  for (int off = 1; off < 256; off <<= 1) {
    int x = (t >= off) ? s[t - off] : 0;
    __syncthreads();
    s[t] += x;
    __syncthreads();
  }
  const int excl = s[t] - v;
  const int node = b * RB + t;
  if (node <= N) offs[node] = segBeg + excl;
  __syncthreads();          // everyone done with h as counts
  h[t] = segBeg + excl;     // reuse h as per-key base
  __syncthreads();

  // pass 2: write from registers
#pragma unroll
  for (int k = 0; k < P2CAP; ++k) {
    if (k < cnt) {
      const int2 r = rec[k];
      pairs[h[r.x & 255] + rk[k]] =
          make_int2((int)(((unsigned)r.x) >> 16), r.y);
    }
  }
  for (int i = segBeg + (P2CAP << 8) + t; i < segEnd; i += 256) {
    const int2 r = tmp[i];
    pairs[h[r.x & 255] + rankG[i]] =
        make_int2((int)(((unsigned)r.x) >> 16), r.y);
  }
}

// ---------------------------------------------------------------------------
// Generic CSR build (N > 65536): hist(+rank) atomics + scan trio + bucket
// ---------------------------------------------------------------------------
__global__ __launch_bounds__(256) void hist_kernel(
    const int* __restrict__ dst, int* __restrict__ deg,
    int* __restrict__ posw, int E) {
  int e = blockIdx.x * 256 + threadIdx.x;
  if (e < E) posw[e] = atomicAdd(&deg[dst[e]], 1);
}

#define SCAN_CHUNK 1024
__global__ __launch_bounds__(256) void scan_part_kernel(
    const int* __restrict__ deg, int* __restrict__ offs,
    int* __restrict__ bsums, int N) {
  __shared__ int s[256];
  const int t = threadIdx.x;
  const int base = blockIdx.x * SCAN_CHUNK + t * 4;
  int v0 = 0, v1 = 0, v2 = 0, v3 = 0;
  if (base + 3 < N) {
    const int4 v = *reinterpret_cast<const int4*>(deg + base);
    v0 = v.x; v1 = v.y; v2 = v.z; v3 = v.w;
  } else {
    if (base + 0 < N) v0 = deg[base + 0];
    if (base + 1 < N) v1 = deg[base + 1];
    if (base + 2 < N) v2 = deg[base + 2];
  }
  const int tsum = v0 + v1 + v2 + v3;
  s[t] = tsum;
  __syncthreads();
  for (int off = 1; off < 256; off <<= 1) {
    int x = (t >= off) ? s[t - off] : 0;
    __syncthreads();
    s[t] += x;
    __syncthreads();
  }
  const int excl = s[t] - tsum;
  if (base + 0 < N) offs[base + 0] = excl;
  if (base + 1 < N) offs[base + 1] = excl + v0;
  if (base + 2 < N) offs[base + 2] = excl + v0 + v1;
  if (base + 3 < N) offs[base + 3] = excl + v0 + v1 + v2;
  if (t == 255) bsums[blockIdx.x] = s[255];
}

__global__ __launch_bounds__(1024) void scan_sums_kernel(
    int* __restrict__ bsums, int* __restrict__ offsN, int nb) {
  __shared__ int s[1024];
  const int t = threadIdx.x;
  const int v = (t < nb) ? bsums[t] : 0;
  s[t] = v;
  __syncthreads();
  for (int off = 1; off < 1024; off <<= 1) {
    int x = (t >= off) ? s[t - off] : 0;
    __syncthreads();
    s[t] += x;
    __syncthreads();
  }
  if (t < nb) bsums[t] = s[t] - v;
  if (t == nb - 1) *offsN = s[t];
}

__global__ __launch_bounds__(256) void scan_add_kernel(
    int* __restrict__ offs, const int* __restrict__ bsums, int N) {
  const int i = blockIdx.x * 256 + threadIdx.x;
  if (i < N) offs[i] += bsums[i >> 10];
}

__global__ __launch_bounds__(256) void bucket_kernel(
    const int* __restrict__ src, const int* __restrict__ dst,
    const float* __restrict__ ew, const int* __restrict__ offs,
    const int* __restrict__ posw, int2* __restrict__ pairs, int E) {
  int e = blockIdx.x * 256 + threadIdx.x;
  if (e < E) {
    const int pos = offs[dst[e]] + posw[e];
    pairs[pos] = make_int2(src[e], __float_as_int(ew[e]));
  }
}

// ---------------------------------------------------------------------------
// FUSED: out[row] = relu(agg(H)[row] + b1) @ W
// Phase A: wave-per-node (16 sequential nodes per wave, no cross-node
// divergence, 16 edges in flight), shfl-reduce across lane-groups.
// Phase B: 64x64 gemm on LDS.
// ---------------------------------------------------------------------------
__global__ __launch_bounds__(256, 4) void agg_gemm_kernel(
    const float* __restrict__ H, const int* __restrict__ offs,
    const int2* __restrict__ pairs, const float* __restrict__ b1,
    const float* __restrict__ W, float* __restrict__ out, int N) {
  __shared__ float sA[64][68];
  __shared__ float sW[64][68];
  const int t = threadIdx.x;
  const int rowBase = blockIdx.x * 64;

#pragma unroll
  for (int i = t * 4; i < 4096; i += 1024) {
    const int k = i >> 6, c = i & 63;
    *reinterpret_cast<float4*>(&sW[k][c]) =
        *reinterpret_cast<const float4*>(W + i);
  }

  const int wv = t >> 6;
  const int lane = t & 63;
  const int g = lane >> 4;
  const int c4 = lane & 15;
  const float4 bb = *reinterpret_cast<const float4*>(b1 + c4 * 4);

  for (int sidx = 0; sidx < 16; ++sidx) {
    const int r = wv * 16 + sidx;
    const int node = rowBase + r;
    float4 a = f4zero();
    if (node < N) {
      const int beg = offs[node], end = offs[node + 1];
      a = gather_rows(H, pairs, beg, end, g, c4);
    }
    a = xor_add(a, 16);
    a = xor_add(a, 32);
    if (g == 0) {
      float4 rr;
      rr.x = fmaxf(a.x + bb.x, 0.f);
      rr.y = fmaxf(a.y + bb.y, 0.f);
      rr.z = fmaxf(a.z + bb.z, 0.f);
      rr.w = fmaxf(a.w + bb.w, 0.f);
      *reinterpret_cast<float4*>(&sA[r][c4 * 4]) = rr;
    }
  }
  __syncthreads();

  const int ty = t >> 4, tx = t & 15;
  float4 acc0 = f4zero(), acc1 = f4zero(), acc2 = f4zero(), acc3 = f4zero();

#pragma unroll 4
  for (int kq = 0; kq < 16; ++kq) {
    const float4 w0 = *reinterpret_cast<const float4*>(&sW[kq * 4 + 0][tx * 4]);
    const float4 w1 = *reinterpret_cast<const float4*>(&sW[kq * 4 + 1][tx * 4]);
    const float4 w2 = *reinterpret_cast<const float4*>(&sW[kq * 4 + 2][tx * 4]);
    const float4 w3 = *reinterpret_cast<const float4*>(&sW[kq * 4 + 3][tx * 4]);
    const float4 a0 = *reinterpret_cast<const float4*>(&sA[ty * 4 + 0][kq * 4]);
    const float4 a1 = *reinterpret_cast<const float4*>(&sA[ty * 4 + 1][kq * 4]);
    const float4 a2 = *reinterpret_cast<const float4*>(&sA[ty * 4 + 2][kq * 4]);
    const float4 a3 = *reinterpret_cast<const float4*>(&sA[ty * 4 + 3][kq * 4]);
#define FMA4(ACC, AV)                                                     \
    ACC.x += AV.x * w0.x + AV.y * w1.x + AV.z * w2.x + AV.w * w3.x;       \
    ACC.y += AV.x * w0.y + AV.y * w1.y + AV.z * w2.y + AV.w * w3.y;       \
    ACC.z += AV.x * w0.z + AV.y * w1.z + AV.z * w2.z + AV.w * w3.z;       \
    ACC.w += AV.x * w0.w + AV.y * w1.w + AV.z * w2.w + AV.w * w3.w;
    FMA4(acc0, a0) FMA4(acc1, a1) FMA4(acc2, a2) FMA4(acc3, a3)
#undef FMA4
  }

  const int row0 = rowBase + ty * 4;
  if (row0 + 0 < N) *reinterpret_cast<float4*>(out + (size_t)(row0 + 0) * D + tx * 4) = acc0;
  if (row0 + 1 < N) *reinterpret_cast<float4*>(out + (size_t)(row0 + 1) * D + tx * 4) = acc1;
  if (row0 + 2 < N) *reinterpret_cast<float4*>(out + (size_t)(row0 + 2) * D + tx * 4) = acc2;
  if (row0 + 3 < N) *reinterpret_cast<float4*>(out + (size_t)(row0 + 3) * D + tx * 4) = acc3;
}

// ---------------------------------------------------------------------------
// Final gather: one wave per node, shfl-reduce, lane-group 0 writes.
// ---------------------------------------------------------------------------
template <bool BIAS>
__global__ __launch_bounds__(256) void wave_agg_kernel(
    const float* __restrict__ H, const int* __restrict__ offs,
    const int2* __restrict__ pairs, const float* __restrict__ bias,
    float* __restrict__ out, int N) {
  const int lane = threadIdx.x & 63;
  const int g = lane >> 4;
  const int c4 = lane & 15;
  const int node = blockIdx.x * 4 + (threadIdx.x >> 6);
  if (node >= N) return;   // uniform per wave
  const int beg = offs[node], end = offs[node + 1];
  float4 a = gather_rows(H, pairs, beg, end, g, c4);
  a = xor_add(a, 16);
  a = xor_add(a, 32);
  if (g == 0) {
    if (BIAS) {
      const float4 b = *reinterpret_cast<const float4*>(bias + c4 * 4);
      a.x += b.x; a.y += b.y; a.z += b.z; a.w += b.w;
    }
    *reinterpret_cast<float4*>(out + (size_t)node * D + c4 * 4) = a;
  }
}

// ---------------------- fallback (atomic scatter) path ---------------------
__global__ __launch_bounds__(256) void scatter_kernel(
    const float* __restrict__ H, const float* __restrict__ ew,
    const int* __restrict__ src, const int* __restrict__ dst,
    float* __restrict__ out, int nEdges) {
  const int tid = blockIdx.x * 256 + threadIdx.x;
  const int e = tid >> 4;
  if (e >= nEdges) return;
  const int c = (tid & 15) * 4;
  const float w = ew[e];
  const float4 v = *reinterpret_cast<const float4*>(H + (size_t)src[e] * D + c);
  float* o = out + (size_t)dst[e] * D + c;
  atomicAdd(o + 0, w * v.x);
  atomicAdd(o + 1, w * v.y);
  atomicAdd(o + 2, w * v.z);
  atomicAdd(o + 3, w * v.w);
}

__global__ __launch_bounds__(256) void fill_bias_kernel(
    float* __restrict__ out, const float* __restrict__ b, int total) {
  int i = blockIdx.x * 256 + threadIdx.x;
  if (i < total) out[i] = b[i & 63];
}

// ---------------------------------------------------------------------------
extern "C" void kernel_launch(void* const* d_in, const int* in_sizes, int n_in,
                              void* d_out, int out_size, void* d_ws,
                              size_t ws_size, hipStream_t stream) {
  const float* X  = (const float*)d_in[0];
  const float* ew = (const float*)d_in[1];
  const float* W1 = (const float*)d_in[2];
  const float* b1 = (const float*)d_in[3];
  const float* W2 = (const float*)d_in[4];
  const float* b2 = (const float*)d_in[5];
  const int*   ei = (const int*)d_in[6];

  const int N = in_sizes[0] / D;   // 50000
  const int E = in_sizes[6] / 2;   // 800000
  const int* src = ei;
  const int* dst = ei + E;
  float* out = (float*)d_out;

  // workspace layout
  char* ws = (char*)d_ws;
  float* buf0 = (float*)ws;                 ws += (size_t)N * D * 4;
  float* buf1 = (float*)ws;                 ws += (size_t)N * D * 4;
  const size_t baseBytes = (size_t)(ws - (char*)d_ws);
  int2*  pairs    = (int2*)ws;              ws += (size_t)E * 8;
  int*   offs     = (int*)ws;               ws += (size_t)(N + 1) * 4;
  int*   countsB  = (int*)ws;               ws += (size_t)NB * RB * 4;
  int*   binBaseG = (int*)ws;               ws += (size_t)(RB + 1) * 4;
  int*   rankG    = (int*)ws;               ws += (size_t)E * 4;
  const size_t needBytes = (size_t)(ws - (char*)d_ws);

  const int gemmBlocks = (N + 63) / 64;
  const int waveBlocks = (N + 3) / 4;
  const int edgeBlocks = (E + 255) / 256;

  if (ws_size >= needBytes) {
    if (N <= NB * RB && (size_t)N * D * 4 >= (size_t)E * 8) {
      // ---- radix build merged with gemm1: no global atomics ----
      int2* tmp = (int2*)buf1;   // buf1 dead until agg_gemm writes it
      const int epb = (E + NB - 1) / NB;
      hist_gemm_kernel<<<NB + gemmBlocks, 256, 0, stream>>>(
          dst, countsB, E, epb, X, W1, buf0, N);
      p1_scatter_kernel<<<NB, 256, 0, stream>>>(src, dst, ew, countsB,
                                                binBaseG, tmp, E, epb);
      p2_kernel<<<RB, 256, 0, stream>>>(tmp, binBaseG, rankG, offs, pairs, N);
    } else {
      // ---- generic build + separate gemm1 ----
      int* deg   = (int*)buf0;
      int* bsums = (int*)buf0 + N;
      int* posw  = (int*)buf1;
      const int nb = (N + SCAN_CHUNK - 1) / SCAN_CHUNK;
      hipMemsetAsync(deg, 0, (size_t)N * 4, stream);
      hist_kernel<<<edgeBlocks, 256, 0, stream>>>(dst, deg, posw, E);
      scan_part_kernel<<<nb, 256, 0, stream>>>(deg, offs, bsums, N);
      scan_sums_kernel<<<1, 1024, 0, stream>>>(bsums, offs + N, nb);
      scan_add_kernel<<<(N + 255) / 256, 256, 0, stream>>>(offs, bsums, N);
      bucket_kernel<<<edgeBlocks, 256, 0, stream>>>(src, dst, ew, offs, posw, pairs, E);
      gemm64_kernel<false><<<gemmBlocks, 256, 0, stream>>>(X, W1, nullptr, buf0, N);
    }

    // ---- fused(agg+relu+gemm2) -> final wave-per-node agg ----
    agg_gemm_kernel<<<gemmBlocks, 256, 0, stream>>>(buf0, offs, pairs, b1, W2, buf1, N);
    wave_agg_kernel<true><<<waveBlocks, 256, 0, stream>>>(buf1, offs, pairs, b2, out, N);
  } else if (ws_size >= baseBytes) {
    // ---- fallback: atomic scatter (slow but correct) ----
    const int scatBlocks = (E * 16 + 255) / 256;
    const int fillBlocks = (N * D + 255) / 256;
    gemm64_kernel<false><<<gemmBlocks, 256, 0, stream>>>(X, W1, nullptr, buf0, N);
    hipMemsetAsync(buf1, 0, (size_t)N * D * 4, stream);
    scatter_kernel<<<scatBlocks, 256, 0, stream>>>(buf0, ew, src, dst, buf1, E);
    gemm64_kernel<true><<<gemmBlocks, 256, 0, stream>>>(buf1, W2, b1, buf0, N);
    fill_bias_kernel<<<fillBlocks, 256, 0, stream>>>(out, b2, N * D);
    scatter_kernel<<<scatBlocks, 256, 0, stream>>>(buf0, ew, src, dst, out, E);
  }
}

// Round 10
// 116.215 us; speedup vs baseline: 1.1268x; 1.1268x over previous
//
#include <hip/hip_runtime.h>

#define D 64  // feature dim for all layers

#define NB 256   // level-1 edge-partition blocks
#define RB 256   // radix bins (dst>>8)
#define P2CAP 20 // register-cached records per thread in p2

__device__ inline float4 f4zero() { return make_float4(0.f, 0.f, 0.f, 0.f); }

// ---------------------------------------------------------------------------
// GEMM: out = f(A) @ W  (generic/fallback paths)
// ---------------------------------------------------------------------------
template <bool PRE>
__global__ __launch_bounds__(256, 4) void gemm64_kernel(
    const float* __restrict__ A, const float* __restrict__ W,
    const float* __restrict__ bpre, float* __restrict__ out, int N) {
  __shared__ float sA[64][68];
  __shared__ float sW[64][68];
  const int t = threadIdx.x;
  const int rowBase = blockIdx.x * 64;

#pragma unroll
  for (int i = t * 4; i < 4096; i += 1024) {
    const int k = i >> 6, c = i & 63;
    *reinterpret_cast<float4*>(&sW[k][c]) =
        *reinterpret_cast<const float4*>(W + i);
  }
#pragma unroll
  for (int i = t * 4; i < 4096; i += 1024) {
    const int r = i >> 6, k = i & 63;
    const int row = rowBase + r;
    float4 a = f4zero();
    if (row < N) a = *reinterpret_cast<const float4*>(A + (size_t)row * D + k);
    if (PRE) {
      const float4 b = *reinterpret_cast<const float4*>(bpre + k);
      a.x = fmaxf(a.x + b.x, 0.f);
      a.y = fmaxf(a.y + b.y, 0.f);
      a.z = fmaxf(a.z + b.z, 0.f);
      a.w = fmaxf(a.w + b.w, 0.f);
    }
    *reinterpret_cast<float4*>(&sA[r][k]) = a;
  }
  __syncthreads();

  const int ty = t >> 4, tx = t & 15;
  float4 acc0 = f4zero(), acc1 = f4zero(), acc2 = f4zero(), acc3 = f4zero();

#pragma unroll 4
  for (int kq = 0; kq < 16; ++kq) {
    const float4 w0 = *reinterpret_cast<const float4*>(&sW[kq * 4 + 0][tx * 4]);
    const float4 w1 = *reinterpret_cast<const float4*>(&sW[kq * 4 + 1][tx * 4]);
    const float4 w2 = *reinterpret_cast<const float4*>(&sW[kq * 4 + 2][tx * 4]);
    const float4 w3 = *reinterpret_cast<const float4*>(&sW[kq * 4 + 3][tx * 4]);
    const float4 a0 = *reinterpret_cast<const float4*>(&sA[ty * 4 + 0][kq * 4]);
    const float4 a1 = *reinterpret_cast<const float4*>(&sA[ty * 4 + 1][kq * 4]);
    const float4 a2 = *reinterpret_cast<const float4*>(&sA[ty * 4 + 2][kq * 4]);
    const float4 a3 = *reinterpret_cast<const float4*>(&sA[ty * 4 + 3][kq * 4]);
#define FMA4(ACC, AV)                                                     \
    ACC.x += AV.x * w0.x + AV.y * w1.x + AV.z * w2.x + AV.w * w3.x;       \
    ACC.y += AV.x * w0.y + AV.y * w1.y + AV.z * w2.y + AV.w * w3.y;       \
    ACC.z += AV.x * w0.z + AV.y * w1.z + AV.z * w2.z + AV.w * w3.z;       \
    ACC.w += AV.x * w0.w + AV.y * w1.w + AV.z * w2.w + AV.w * w3.w;
    FMA4(acc0, a0) FMA4(acc1, a1) FMA4(acc2, a2) FMA4(acc3, a3)
#undef FMA4
  }

  const int row0 = rowBase + ty * 4;
  if (row0 + 0 < N) *reinterpret_cast<float4*>(out + (size_t)(row0 + 0) * D + tx * 4) = acc0;
  if (row0 + 1 < N) *reinterpret_cast<float4*>(out + (size_t)(row0 + 1) * D + tx * 4) = acc1;
  if (row0 + 2 < N) *reinterpret_cast<float4*>(out + (size_t)(row0 + 2) * D + tx * 4) = acc2;
  if (row0 + 3 < N) *reinterpret_cast<float4*>(out + (size_t)(row0 + 3) * D + tx * 4) = acc3;
}

// ---------------------------------------------------------------------------
// MERGED kernel 1 (radix path): blocks [0,NB) coarse-histogram; rest gemm1.
// ---------------------------------------------------------------------------
__global__ __launch_bounds__(256, 4) void hist_gemm_kernel(
    const int* __restrict__ dst, int* __restrict__ countsB, int E, int epb,
    const float* __restrict__ A, const float* __restrict__ W,
    float* __restrict__ out, int N) {
  __shared__ float sA[64][68];
  __shared__ float sW[64][68];
  const int t = threadIdx.x;

  if ((int)blockIdx.x < NB) {
    int* h = reinterpret_cast<int*>(&sA[0][0]);
    h[t] = 0;
    __syncthreads();
    const int base = blockIdx.x * epb;
    const int lim = min(base + epb, E);
    for (int i = base + t; i < lim; i += 256) atomicAdd(&h[dst[i] >> 8], 1);
    __syncthreads();
    countsB[blockIdx.x * RB + t] = h[t];
    return;
  }

  const int rowBase = ((int)blockIdx.x - NB) * 64;
#pragma unroll
  for (int i = t * 4; i < 4096; i += 1024) {
    const int k = i >> 6, c = i & 63;
    *reinterpret_cast<float4*>(&sW[k][c]) =
        *reinterpret_cast<const float4*>(W + i);
  }
#pragma unroll
  for (int i = t * 4; i < 4096; i += 1024) {
    const int r = i >> 6, k = i & 63;
    const int row = rowBase + r;
    float4 a = f4zero();
    if (row < N) a = *reinterpret_cast<const float4*>(A + (size_t)row * D + k);
    *reinterpret_cast<float4*>(&sA[r][k]) = a;
  }
  __syncthreads();

  const int ty = t >> 4, tx = t & 15;
  float4 acc0 = f4zero(), acc1 = f4zero(), acc2 = f4zero(), acc3 = f4zero();

#pragma unroll 4
  for (int kq = 0; kq < 16; ++kq) {
    const float4 w0 = *reinterpret_cast<const float4*>(&sW[kq * 4 + 0][tx * 4]);
    const float4 w1 = *reinterpret_cast<const float4*>(&sW[kq * 4 + 1][tx * 4]);
    const float4 w2 = *reinterpret_cast<const float4*>(&sW[kq * 4 + 2][tx * 4]);
    const float4 w3 = *reinterpret_cast<const float4*>(&sW[kq * 4 + 3][tx * 4]);
    const float4 a0 = *reinterpret_cast<const float4*>(&sA[ty * 4 + 0][kq * 4]);
    const float4 a1 = *reinterpret_cast<const float4*>(&sA[ty * 4 + 1][kq * 4]);
    const float4 a2 = *reinterpret_cast<const float4*>(&sA[ty * 4 + 2][kq * 4]);
    const float4 a3 = *reinterpret_cast<const float4*>(&sA[ty * 4 + 3][kq * 4]);
#define FMA4(ACC, AV)                                                     \
    ACC.x += AV.x * w0.x + AV.y * w1.x + AV.z * w2.x + AV.w * w3.x;       \
    ACC.y += AV.x * w0.y + AV.y * w1.y + AV.z * w2.y + AV.w * w3.y;       \
    ACC.z += AV.x * w0.z + AV.y * w1.z + AV.z * w2.z + AV.w * w3.z;       \
    ACC.w += AV.x * w0.w + AV.y * w1.w + AV.z * w2.w + AV.w * w3.w;
    FMA4(acc0, a0) FMA4(acc1, a1) FMA4(acc2, a2) FMA4(acc3, a3)
#undef FMA4
  }

  const int row0 = rowBase + ty * 4;
  if (row0 + 0 < N) *reinterpret_cast<float4*>(out + (size_t)(row0 + 0) * D + tx * 4) = acc0;
  if (row0 + 1 < N) *reinterpret_cast<float4*>(out + (size_t)(row0 + 1) * D + tx * 4) = acc1;
  if (row0 + 2 < N) *reinterpret_cast<float4*>(out + (size_t)(row0 + 2) * D + tx * 4) = acc2;
  if (row0 + 3 < N) *reinterpret_cast<float4*>(out + (size_t)(row0 + 3) * D + tx * 4) = acc3;
}

// ---------------------------------------------------------------------------
// p1_scatter (radix): derives bin bases from block-major countsB, scatters
// records into coarse buckets. Block 0 publishes binBase[257] for p2.
// ---------------------------------------------------------------------------
__global__ __launch_bounds__(256) void p1_scatter_kernel(
    const int* __restrict__ src, const int* __restrict__ dst,
    const float* __restrict__ ew, const int* __restrict__ countsB,
    int* __restrict__ binBaseG, int2* __restrict__ tmp, int E, int epb) {
  __shared__ int s[RB];
  __shared__ int cur[RB];
  const int t = threadIdx.x;
  const int b = blockIdx.x;

  int total = 0, pre = 0;
#pragma unroll 8
  for (int i = 0; i < NB; ++i) {
    const int c = countsB[i * RB + t];
    if (i == b) pre = total;
    total += c;
  }
  s[t] = total;
  __syncthreads();
  for (int off = 1; off < 256; off <<= 1) {
    int x = (t >= off) ? s[t - off] : 0;
    __syncthreads();
    s[t] += x;
    __syncthreads();
  }
  const int binBase = s[t] - total;
  cur[t] = binBase + pre;
  if (b == 0) {
    binBaseG[t] = binBase;
    if (t == 255) binBaseG[256] = s[255];
  }
  __syncthreads();

  const int base = b * epb;
  const int lim = min(base + epb, E);
  for (int i = base + t; i < lim; i += 256) {
    const int d = dst[i];
    const unsigned sv = (unsigned)src[i];
    const float w = ew[i];
    const int pos = atomicAdd(&cur[d >> 8], 1);   // LDS atomic
    tmp[pos] = make_int2((int)((unsigned)d | (sv << 16)), __float_as_int(w));
  }
}

// ---------------------------------------------------------------------------
// p2 (radix): SINGLE global pass. Records + their LDS-atomic ranks cached in
// registers (statically indexed, P2CAP each); overflow spills to rankG
// (never hit at this distribution). Write pos = base[key] + rank.
// ---------------------------------------------------------------------------
__global__ __launch_bounds__(256) void p2_kernel(
    const int2* __restrict__ tmp, const int* __restrict__ binBaseG,
    int* __restrict__ rankG,
    int* __restrict__ offs, int2* __restrict__ pairs, int N) {
  __shared__ int h[RB];
  __shared__ int s[RB];
  const int t = threadIdx.x;
  const int b = blockIdx.x;
  const int segBeg = binBaseG[b];
  const int segEnd = binBaseG[b + 1];
  const int segLen = segEnd - segBeg;

  h[t] = 0;
  __syncthreads();

  const int cnt = (segLen - t + 255) >> 8;   // my record count (>=0)
  int2 rec[P2CAP];
  int  rk[P2CAP];
#pragma unroll
  for (int k = 0; k < P2CAP; ++k) {
    if (k < cnt) {
      const int i = segBeg + t + (k << 8);
      const int2 r = tmp[i];
      rec[k] = r;
      rk[k] = atomicAdd(&h[r.x & 255], 1);
    }
  }
  for (int i = segBeg + (P2CAP << 8) + t; i < segEnd; i += 256)
    rankG[i] = atomicAdd(&h[tmp[i].x & 255], 1);   // overflow (rare)
  __syncthreads();

  const int v = h[t];
  s[t] = v;
  __syncthreads();
  for (int off = 1; off < 256; off <<= 1) {
    int x = (t >= off) ? s[t - off] : 0;
    __syncthreads();
    s[t] += x;
    __syncthreads();
  }
  const int excl = s[t] - v;
  const int node = b * RB + t;
  if (node <= N) offs[node] = segBeg + excl;
  __syncthreads();
  h[t] = segBeg + excl;     // reuse h as per-key base
  __syncthreads();

#pragma unroll
  for (int k = 0; k < P2CAP; ++k) {
    if (k < cnt) {
      const int2 r = rec[k];
      pairs[h[r.x & 255] + rk[k]] =
          make_int2((int)(((unsigned)r.x) >> 16), r.y);
    }
  }
  for (int i = segBeg + (P2CAP << 8) + t; i < segEnd; i += 256) {
    const int2 r = tmp[i];
    pairs[h[r.x & 255] + rankG[i]] =
        make_int2((int)(((unsigned)r.x) >> 16), r.y);
  }
}

// ---------------------------------------------------------------------------
// Generic CSR build (N > 65536): hist(+rank) atomics + scan trio + bucket
// ---------------------------------------------------------------------------
__global__ __launch_bounds__(256) void hist_kernel(
    const int* __restrict__ dst, int* __restrict__ deg,
    int* __restrict__ posw, int E) {
  int e = blockIdx.x * 256 + threadIdx.x;
  if (e < E) posw[e] = atomicAdd(&deg[dst[e]], 1);
}

#define SCAN_CHUNK 1024
__global__ __launch_bounds__(256) void scan_part_kernel(
    const int* __restrict__ deg, int* __restrict__ offs,
    int* __restrict__ bsums, int N) {
  __shared__ int s[256];
  const int t = threadIdx.x;
  const int base = blockIdx.x * SCAN_CHUNK + t * 4;
  int v0 = 0, v1 = 0, v2 = 0, v3 = 0;
  if (base + 3 < N) {
    const int4 v = *reinterpret_cast<const int4*>(deg + base);
    v0 = v.x; v1 = v.y; v2 = v.z; v3 = v.w;
  } else {
    if (base + 0 < N) v0 = deg[base + 0];
    if (base + 1 < N) v1 = deg[base + 1];
    if (base + 2 < N) v2 = deg[base + 2];
  }
  const int tsum = v0 + v1 + v2 + v3;
  s[t] = tsum;
  __syncthreads();
  for (int off = 1; off < 256; off <<= 1) {
    int x = (t >= off) ? s[t - off] : 0;
    __syncthreads();
    s[t] += x;
    __syncthreads();
  }
  const int excl = s[t] - tsum;
  if (base + 0 < N) offs[base + 0] = excl;
  if (base + 1 < N) offs[base + 1] = excl + v0;
  if (base + 2 < N) offs[base + 2] = excl + v0 + v1;
  if (base + 3 < N) offs[base + 3] = excl + v0 + v1 + v2;
  if (t == 255) bsums[blockIdx.x] = s[255];
}

__global__ __launch_bounds__(1024) void scan_sums_kernel(
    int* __restrict__ bsums, int* __restrict__ offsN, int nb) {
  __shared__ int s[1024];
  const int t = threadIdx.x;
  const int v = (t < nb) ? bsums[t] : 0;
  s[t] = v;
  __syncthreads();
  for (int off = 1; off < 1024; off <<= 1) {
    int x = (t >= off) ? s[t - off] : 0;
    __syncthreads();
    s[t] += x;
    __syncthreads();
  }
  if (t < nb) bsums[t] = s[t] - v;
  if (t == nb - 1) *offsN = s[t];
}

__global__ __launch_bounds__(256) void scan_add_kernel(
    int* __restrict__ offs, const int* __restrict__ bsums, int N) {
  const int i = blockIdx.x * 256 + threadIdx.x;
  if (i < N) offs[i] += bsums[i >> 10];
}

__global__ __launch_bounds__(256) void bucket_kernel(
    const int* __restrict__ src, const int* __restrict__ dst,
    const float* __restrict__ ew, const int* __restrict__ offs,
    const int* __restrict__ posw, int2* __restrict__ pairs, int E) {
  int e = blockIdx.x * 256 + threadIdx.x;
  if (e < E) {
    const int pos = offs[dst[e]] + posw[e];
    pairs[pos] = make_int2(src[e], __float_as_int(ew[e]));
  }
}

// ---------------------------------------------------------------------------
// FUSED: out[row] = relu(agg(H)[row] + b1) @ W  (R8-proven gather structure:
// 16 lanes/node, float4/lane, 4 independent accumulator chains — robust MLP
// at any degree >= 4; R9's wave-per-node variant regressed on low-deg tails).
// ---------------------------------------------------------------------------
__global__ __launch_bounds__(256, 4) void agg_gemm_kernel(
    const float* __restrict__ H, const int* __restrict__ offs,
    const int2* __restrict__ pairs, const float* __restrict__ b1,
    const float* __restrict__ W, float* __restrict__ out, int N) {
  __shared__ float sA[64][68];
  __shared__ float sW[64][68];
  const int t = threadIdx.x;
  const int rowBase = blockIdx.x * 64;

#pragma unroll
  for (int i = t * 4; i < 4096; i += 1024) {
    const int k = i >> 6, c = i & 63;
    *reinterpret_cast<float4*>(&sW[k][c]) =
        *reinterpret_cast<const float4*>(W + i);
  }

  const int l4 = t & 15;
  const int sub = t >> 4;
  const float4 bb = *reinterpret_cast<const float4*>(b1 + l4 * 4);
#pragma unroll
  for (int p = 0; p < 4; ++p) {
    const int r = p * 16 + sub;
    const int node = rowBase + r;
    float4 A0 = f4zero(), A1 = f4zero(), A2 = f4zero(), A3 = f4zero();
    if (node < N) {
      const int beg = offs[node], end = offs[node + 1];
      int i = beg;
      for (; i + 4 <= end; i += 4) {
        const int2 p0 = pairs[i], p1 = pairs[i + 1], p2 = pairs[i + 2], p3 = pairs[i + 3];
        const float4 v0 = *reinterpret_cast<const float4*>(H + (size_t)p0.x * D + l4 * 4);
        const float4 v1 = *reinterpret_cast<const float4*>(H + (size_t)p1.x * D + l4 * 4);
        const float4 v2 = *reinterpret_cast<const float4*>(H + (size_t)p2.x * D + l4 * 4);
        const float4 v3 = *reinterpret_cast<const float4*>(H + (size_t)p3.x * D + l4 * 4);
        const float w0 = __int_as_float(p0.y), w1 = __int_as_float(p1.y);
        const float w2 = __int_as_float(p2.y), w3 = __int_as_float(p3.y);
        A0.x += w0 * v0.x; A0.y += w0 * v0.y; A0.z += w0 * v0.z; A0.w += w0 * v0.w;
        A1.x += w1 * v1.x; A1.y += w1 * v1.y; A1.z += w1 * v1.z; A1.w += w1 * v1.w;
        A2.x += w2 * v2.x; A2.y += w2 * v2.y; A2.z += w2 * v2.z; A2.w += w2 * v2.w;
        A3.x += w3 * v3.x; A3.y += w3 * v3.y; A3.z += w3 * v3.z; A3.w += w3 * v3.w;
      }
      for (; i < end; ++i) {
        const int2 pp = pairs[i];
        const float4 v = *reinterpret_cast<const float4*>(H + (size_t)pp.x * D + l4 * 4);
        const float w = __int_as_float(pp.y);
        A0.x += w * v.x; A0.y += w * v.y; A0.z += w * v.z; A0.w += w * v.w;
      }
    }
    float4 rr;
    rr.x = fmaxf((A0.x + A1.x) + (A2.x + A3.x) + bb.x, 0.f);
    rr.y = fmaxf((A0.y + A1.y) + (A2.y + A3.y) + bb.y, 0.f);
    rr.z = fmaxf((A0.z + A1.z) + (A2.z + A3.z) + bb.z, 0.f);
    rr.w = fmaxf((A0.w + A1.w) + (A2.w + A3.w) + bb.w, 0.f);
    *reinterpret_cast<float4*>(&sA[r][l4 * 4]) = rr;
  }
  __syncthreads();

  const int ty = t >> 4, tx = t & 15;
  float4 acc0 = f4zero(), acc1 = f4zero(), acc2 = f4zero(), acc3 = f4zero();

#pragma unroll 4
  for (int kq = 0; kq < 16; ++kq) {
    const float4 w0 = *reinterpret_cast<const float4*>(&sW[kq * 4 + 0][tx * 4]);
    const float4 w1 = *reinterpret_cast<const float4*>(&sW[kq * 4 + 1][tx * 4]);
    const float4 w2 = *reinterpret_cast<const float4*>(&sW[kq * 4 + 2][tx * 4]);
    const float4 w3 = *reinterpret_cast<const float4*>(&sW[kq * 4 + 3][tx * 4]);
    const float4 a0 = *reinterpret_cast<const float4*>(&sA[ty * 4 + 0][kq * 4]);
    const float4 a1 = *reinterpret_cast<const float4*>(&sA[ty * 4 + 1][kq * 4]);
    const float4 a2 = *reinterpret_cast<const float4*>(&sA[ty * 4 + 2][kq * 4]);
    const float4 a3 = *reinterpret_cast<const float4*>(&sA[ty * 4 + 3][kq * 4]);
#define FMA4(ACC, AV)                                                     \
    ACC.x += AV.x * w0.x + AV.y * w1.x + AV.z * w2.x + AV.w * w3.x;       \
    ACC.y += AV.x * w0.y + AV.y * w1.y + AV.z * w2.y + AV.w * w3.y;       \
    ACC.z += AV.x * w0.z + AV.y * w1.z + AV.z * w2.z + AV.w * w3.z;       \
    ACC.w += AV.x * w0.w + AV.y * w1.w + AV.z * w2.w + AV.w * w3.w;
    FMA4(acc0, a0) FMA4(acc1, a1) FMA4(acc2, a2) FMA4(acc3, a3)
#undef FMA4
  }

  const int row0 = rowBase + ty * 4;
  if (row0 + 0 < N) *reinterpret_cast<float4*>(out + (size_t)(row0 + 0) * D + tx * 4) = acc0;
  if (row0 + 1 < N) *reinterpret_cast<float4*>(out + (size_t)(row0 + 1) * D + tx * 4) = acc1;
  if (row0 + 2 < N) *reinterpret_cast<float4*>(out + (size_t)(row0 + 2) * D + tx * 4) = acc2;
  if (row0 + 3 < N) *reinterpret_cast<float4*>(out + (size_t)(row0 + 3) * D + tx * 4) = acc3;
}

// ---------------------------------------------------------------------------
// Gather-aggregate (final layer): 16 lanes/node, float4/lane, 4-deep MLP.
// ---------------------------------------------------------------------------
template <bool BIAS>
__global__ __launch_bounds__(256) void gather_agg_kernel(
    const float* __restrict__ H, const int* __restrict__ offs,
    const int2* __restrict__ pairs,
    const float* __restrict__ bias, float* __restrict__ out, int N) {
  const int l4 = threadIdx.x & 15;
  const int node = blockIdx.x * 16 + (threadIdx.x >> 4);
  if (node >= N) return;
  const int beg = offs[node], end = offs[node + 1];
  float4 A0 = f4zero(), A1 = f4zero(), A2 = f4zero(), A3 = f4zero();
  int i = beg;
  for (; i + 4 <= end; i += 4) {
    const int2 p0 = pairs[i], p1 = pairs[i + 1], p2 = pairs[i + 2], p3 = pairs[i + 3];
    const float4 v0 = *reinterpret_cast<const float4*>(H + (size_t)p0.x * D + l4 * 4);
    const float4 v1 = *reinterpret_cast<const float4*>(H + (size_t)p1.x * D + l4 * 4);
    const float4 v2 = *reinterpret_cast<const float4*>(H + (size_t)p2.x * D + l4 * 4);
    const float4 v3 = *reinterpret_cast<const float4*>(H + (size_t)p3.x * D + l4 * 4);
    const float w0 = __int_as_float(p0.y), w1 = __int_as_float(p1.y);
    const float w2 = __int_as_float(p2.y), w3 = __int_as_float(p3.y);
    A0.x += w0 * v0.x; A0.y += w0 * v0.y; A0.z += w0 * v0.z; A0.w += w0 * v0.w;
    A1.x += w1 * v1.x; A1.y += w1 * v1.y; A1.z += w1 * v1.z; A1.w += w1 * v1.w;
    A2.x += w2 * v2.x; A2.y += w2 * v2.y; A2.z += w2 * v2.z; A2.w += w2 * v2.w;
    A3.x += w3 * v3.x; A3.y += w3 * v3.y; A3.z += w3 * v3.z; A3.w += w3 * v3.w;
  }
  for (; i < end; ++i) {
    const int2 p = pairs[i];
    const float4 v = *reinterpret_cast<const float4*>(H + (size_t)p.x * D + l4 * 4);
    const float w = __int_as_float(p.y);
    A0.x += w * v.x; A0.y += w * v.y; A0.z += w * v.z; A0.w += w * v.w;
  }
  float4 r;
  r.x = (A0.x + A1.x) + (A2.x + A3.x);
  r.y = (A0.y + A1.y) + (A2.y + A3.y);
  r.z = (A0.z + A1.z) + (A2.z + A3.z);
  r.w = (A0.w + A1.w) + (A2.w + A3.w);
  if (BIAS) {
    const float4 b = *reinterpret_cast<const float4*>(bias + l4 * 4);
    r.x += b.x; r.y += b.y; r.z += b.z; r.w += b.w;
  }
  *reinterpret_cast<float4*>(out + (size_t)node * D + l4 * 4) = r;
}

// ---------------------- fallback (atomic scatter) path ---------------------
__global__ __launch_bounds__(256) void scatter_kernel(
    const float* __restrict__ H, const float* __restrict__ ew,
    const int* __restrict__ src, const int* __restrict__ dst,
    float* __restrict__ out, int nEdges) {
  const int tid = blockIdx.x * 256 + threadIdx.x;
  const int e = tid >> 4;
  if (e >= nEdges) return;
  const int c = (tid & 15) * 4;
  const float w = ew[e];
  const float4 v = *reinterpret_cast<const float4*>(H + (size_t)src[e] * D + c);
  float* o = out + (size_t)dst[e] * D + c;
  atomicAdd(o + 0, w * v.x);
  atomicAdd(o + 1, w * v.y);
  atomicAdd(o + 2, w * v.z);
  atomicAdd(o + 3, w * v.w);
}

__global__ __launch_bounds__(256) void fill_bias_kernel(
    float* __restrict__ out, const float* __restrict__ b, int total) {
  int i = blockIdx.x * 256 + threadIdx.x;
  if (i < total) out[i] = b[i & 63];
}

// ---------------------------------------------------------------------------
extern "C" void kernel_launch(void* const* d_in, const int* in_sizes, int n_in,
                              void* d_out, int out_size, void* d_ws,
                              size_t ws_size, hipStream_t stream) {
  const float* X  = (const float*)d_in[0];
  const float* ew = (const float*)d_in[1];
  const float* W1 = (const float*)d_in[2];
  const float* b1 = (const float*)d_in[3];
  const float* W2 = (const float*)d_in[4];
  const float* b2 = (const float*)d_in[5];
  const int*   ei = (const int*)d_in[6];

  const int N = in_sizes[0] / D;   // 50000
  const int E = in_sizes[6] / 2;   // 800000
  const int* src = ei;
  const int* dst = ei + E;
  float* out = (float*)d_out;

  // workspace layout
  char* ws = (char*)d_ws;
  float* buf0 = (float*)ws;                 ws += (size_t)N * D * 4;
  float* buf1 = (float*)ws;                 ws += (size_t)N * D * 4;
  const size_t baseBytes = (size_t)(ws - (char*)d_ws);
  int2*  pairs    = (int2*)ws;              ws += (size_t)E * 8;
  int*   offs     = (int*)ws;               ws += (size_t)(N + 1) * 4;
  int*   countsB  = (int*)ws;               ws += (size_t)NB * RB * 4;
  int*   binBaseG = (int*)ws;               ws += (size_t)(RB + 1) * 4;
  int*   rankG    = (int*)ws;               ws += (size_t)E * 4;
  const size_t needBytes = (size_t)(ws - (char*)d_ws);

  const int gemmBlocks = (N + 63) / 64;
  const int aggBlocks  = (N + 15) / 16;
  const int edgeBlocks = (E + 255) / 256;

  if (ws_size >= needBytes) {
    if (N <= NB * RB && (size_t)N * D * 4 >= (size_t)E * 8) {
      // ---- radix build merged with gemm1: no global atomics ----
      int2* tmp = (int2*)buf1;   // buf1 dead until agg_gemm writes it
      const int epb = (E + NB - 1) / NB;
      hist_gemm_kernel<<<NB + gemmBlocks, 256, 0, stream>>>(
          dst, countsB, E, epb, X, W1, buf0, N);
      p1_scatter_kernel<<<NB, 256, 0, stream>>>(src, dst, ew, countsB,
                                                binBaseG, tmp, E, epb);
      p2_kernel<<<RB, 256, 0, stream>>>(tmp, binBaseG, rankG, offs, pairs, N);
    } else {
      // ---- generic build + separate gemm1 ----
      int* deg   = (int*)buf0;
      int* bsums = (int*)buf0 + N;
      int* posw  = (int*)buf1;
      const int nb = (N + SCAN_CHUNK - 1) / SCAN_CHUNK;
      hipMemsetAsync(deg, 0, (size_t)N * 4, stream);
      hist_kernel<<<edgeBlocks, 256, 0, stream>>>(dst, deg, posw, E);
      scan_part_kernel<<<nb, 256, 0, stream>>>(deg, offs, bsums, N);
      scan_sums_kernel<<<1, 1024, 0, stream>>>(bsums, offs + N, nb);
      scan_add_kernel<<<(N + 255) / 256, 256, 0, stream>>>(offs, bsums, N);
      bucket_kernel<<<edgeBlocks, 256, 0, stream>>>(src, dst, ew, offs, posw, pairs, E);
      gemm64_kernel<false><<<gemmBlocks, 256, 0, stream>>>(X, W1, nullptr, buf0, N);
    }

    // ---- fused(agg+relu+gemm2) -> final gather ----
    agg_gemm_kernel<<<gemmBlocks, 256, 0, stream>>>(buf0, offs, pairs, b1, W2, buf1, N);
    gather_agg_kernel<true><<<aggBlocks, 256, 0, stream>>>(buf1, offs, pairs, b2, out, N);
  } else if (ws_size >= baseBytes) {
    // ---- fallback: atomic scatter (slow but correct) ----
    const int scatBlocks = (E * 16 + 255) / 256;
    const int fillBlocks = (N * D + 255) / 256;
    gemm64_kernel<false><<<gemmBlocks, 256, 0, stream>>>(X, W1, nullptr, buf0, N);
    hipMemsetAsync(buf1, 0, (size_t)N * D * 4, stream);
    scatter_kernel<<<scatBlocks, 256, 0, stream>>>(buf0, ew, src, dst, buf1, E);
    gemm64_kernel<true><<<gemmBlocks, 256, 0, stream>>>(buf1, W2, b1, buf0, N);
    fill_bias_kernel<<<fillBlocks, 256, 0, stream>>>(out, b2, N * D);
    scatter_kernel<<<scatBlocks, 256, 0, stream>>>(buf0, ew, src, dst, out, E);
  }
}